// Round 1
// baseline (574.800 us; speedup 1.0000x reference)
//
#include <hip/hip_runtime.h>
#include <hip/hip_bf16.h>
#include <cstdint>

#define TOK 100352
#define HID 384
#define NQKV 1152
#define NHEADS 12
#define HDIM 32

typedef __attribute__((ext_vector_type(8))) short bhalf8;
typedef __attribute__((ext_vector_type(4))) float f32x4;

__device__ __forceinline__ ushort f2bf(float f) {
  uint32_t u = __float_as_uint(f);
  return (ushort)((u + 0x7FFFu + ((u >> 16) & 1u)) >> 16);
}

// C = A @ B (bf16 MFMA, fp32 accum). A: [M][K] fp32 or bf16. B: [K][N] fp32.
// OUT_F32_BIAS: write fp32 + bias[col]; else write bf16.
template<bool A_BF16, bool OUT_F32_BIAS>
__global__ __launch_bounds__(256)
void gemm_mfma(const void* __restrict__ Ap, const float* __restrict__ Bp,
               const float* __restrict__ bias, void* __restrict__ Cp,
               const int M, const int N, const int K)
{
  __shared__ ushort As[128 * 64];  // [m][k] bf16, XOR-swizzled 16B slots
  __shared__ ushort Bs[128 * 64];  // [n][k] bf16 (transposed), same swizzle

  const int tid = threadIdx.x;
  const int lane = tid & 63;
  const int wave = tid >> 6;
  const int wm = wave >> 1, wn = wave & 1;
  const int l15 = lane & 15, l16 = lane >> 4;
  const int row0 = blockIdx.y * 128;
  const int col0 = blockIdx.x * 128;

  f32x4 acc[4][4] = {};

  for (int ko = 0; ko < K; ko += 64) {
    if (ko) __syncthreads();
    // ---- stage A tile (128 x 64) ----
    #pragma unroll
    for (int it = 0; it < 4; ++it) {
      const int c = tid + 256 * it;
      const int m = c >> 3;
      const int k8 = (c & 7) * 8;
      bhalf8 v;
      if (A_BF16) {
        const ushort* gA = (const ushort*)Ap + (size_t)(row0 + m) * K + ko + k8;
        v = *(const bhalf8*)gA;
      } else {
        const float* gA = (const float*)Ap + (size_t)(row0 + m) * K + ko + k8;
        const float4 f0 = *(const float4*)gA;
        const float4 f1 = *(const float4*)(gA + 4);
        v[0] = (short)f2bf(f0.x); v[1] = (short)f2bf(f0.y);
        v[2] = (short)f2bf(f0.z); v[3] = (short)f2bf(f0.w);
        v[4] = (short)f2bf(f1.x); v[5] = (short)f2bf(f1.y);
        v[6] = (short)f2bf(f1.z); v[7] = (short)f2bf(f1.w);
      }
      const int off = m * 128 + ((k8 * 2) ^ ((m & 7) << 4));
      *(bhalf8*)((char*)As + off) = v;
    }
    // ---- stage B tile (64 x 128), transposed into [n][k] ----
    #pragma unroll
    for (int it = 0; it < 4; ++it) {
      const int c = tid + 256 * it;
      const int n = c & 127;
      const int k8 = (c >> 7) * 8;
      const float* gB = Bp + (size_t)(ko + k8) * N + col0 + n;
      bhalf8 v;
      #pragma unroll
      for (int e = 0; e < 8; ++e) v[e] = (short)f2bf(gB[(size_t)e * N]);
      const int off = n * 128 + ((k8 * 2) ^ ((n & 7) << 4));
      *(bhalf8*)((char*)Bs + off) = v;
    }
    __syncthreads();
    // ---- MFMA ----
    #pragma unroll
    for (int kk = 0; kk < 64; kk += 32) {
      bhalf8 af[4], bfr[4];
      const int kb = (kk + l16 * 8) * 2;
      #pragma unroll
      for (int f = 0; f < 4; ++f) {
        const int m = wm * 64 + f * 16 + l15;
        af[f] = *(const bhalf8*)((const char*)As + m * 128 + (kb ^ ((m & 7) << 4)));
        const int n = wn * 64 + f * 16 + l15;
        bfr[f] = *(const bhalf8*)((const char*)Bs + n * 128 + (kb ^ ((n & 7) << 4)));
      }
      #pragma unroll
      for (int fm = 0; fm < 4; ++fm)
        #pragma unroll
        for (int fn = 0; fn < 4; ++fn)
          acc[fm][fn] = __builtin_amdgcn_mfma_f32_16x16x32_bf16(af[fm], bfr[fn], acc[fm][fn], 0, 0, 0);
    }
  }

  // ---- epilogue: D row=(lane>>4)*4+i, col=lane&15 ----
  #pragma unroll
  for (int fm = 0; fm < 4; ++fm) {
    const int rb = row0 + wm * 64 + fm * 16 + l16 * 4;
    #pragma unroll
    for (int fn = 0; fn < 4; ++fn) {
      const int cc = col0 + wn * 64 + fn * 16 + l15;
      const float badd = OUT_F32_BIAS ? bias[cc] : 0.f;
      #pragma unroll
      for (int i = 0; i < 4; ++i) {
        const float vv = acc[fm][fn][i] + badd;
        if (OUT_F32_BIAS) {
          ((float*)Cp)[(size_t)(rb + i) * N + cc] = vv;
        } else {
          ((ushort*)Cp)[(size_t)(rb + i) * N + cc] = f2bf(vv);
        }
      }
    }
  }
}

// One wave per (window, head). 49 tokens padded to 64.
__global__ __launch_bounds__(64)
void win_attn(const ushort* __restrict__ qkv, const float* __restrict__ bias_table,
              ushort* __restrict__ attn_out)
{
  __shared__ ushort Qs[64 * 32];
  __shared__ ushort Ks[64 * 32];
  __shared__ ushort Vt[32 * 64];  // [d][token]
  __shared__ ushort Ps[64 * 64];

  const int lane = threadIdx.x;
  const int l15 = lane & 15, l16 = lane >> 4;
  const int bid = blockIdx.x;
  const int head = bid % NHEADS;
  const int win = bid / NHEADS;
  const int b  = win >> 6;
  const int wi = (win >> 3) & 7;
  const int wj = win & 7;

  {
    const bhalf8 z = {0,0,0,0,0,0,0,0};
    #pragma unroll
    for (int i = 0; i < 4; ++i) {
      ((bhalf8*)Qs)[lane + 64 * i] = z;
      ((bhalf8*)Ks)[lane + 64 * i] = z;
      ((bhalf8*)Vt)[lane + 64 * i] = z;
    }
  }
  __syncthreads();

  if (lane < 49) {
    const int grow = b * 3136 + (wi * 7 + lane / 7) * 56 + (wj * 7 + lane % 7);
    const ushort* base = qkv + (size_t)grow * NQKV + head * HDIM;
    #pragma unroll
    for (int c2 = 0; c2 < 4; ++c2) {
      *(bhalf8*)&Qs[lane * 32 + c2 * 8] = *(const bhalf8*)(base + c2 * 8);
      *(bhalf8*)&Ks[lane * 32 + c2 * 8] = *(const bhalf8*)(base + 384 + c2 * 8);
    }
    #pragma unroll
    for (int d = 0; d < 32; ++d) Vt[d * 64 + lane] = base[768 + d];
  }
  __syncthreads();

  // S = Q @ K^T  (64x64, K=32: one MFMA per fragment)
  bhalf8 qf[4], kf[4];
  #pragma unroll
  for (int f = 0; f < 4; ++f) {
    qf[f] = *(const bhalf8*)&Qs[(f * 16 + l15) * 32 + l16 * 8];
    kf[f] = *(const bhalf8*)&Ks[(f * 16 + l15) * 32 + l16 * 8];
  }
  const f32x4 fz = {};
  f32x4 s[4][4];
  #pragma unroll
  for (int fm = 0; fm < 4; ++fm)
    #pragma unroll
    for (int fn = 0; fn < 4; ++fn)
      s[fm][fn] = __builtin_amdgcn_mfma_f32_16x16x32_bf16(qf[fm], kf[fn], fz, 0, 0, 0);

  const float scale = 0.17677669529663687f; // 32^-0.5
  const int colv[4] = {l15, 16 + l15, 32 + l15, 48 + l15};

  // softmax per row (16-lane groups hold one row across l15), bias AFTER softmax
  #pragma unroll
  for (int fm = 0; fm < 4; ++fm) {
    #pragma unroll
    for (int i = 0; i < 4; ++i) {
      const int r = fm * 16 + l16 * 4 + i;
      float val[4];
      float mx = -1e30f;
      #pragma unroll
      for (int fn = 0; fn < 4; ++fn) {
        val[fn] = s[fm][fn][i] * scale;
        if (colv[fn] < 49) mx = fmaxf(mx, val[fn]);
      }
      #pragma unroll
      for (int off = 1; off < 16; off <<= 1) mx = fmaxf(mx, __shfl_xor(mx, off));
      float e[4]; float sum = 0.f;
      #pragma unroll
      for (int fn = 0; fn < 4; ++fn) {
        e[fn] = (colv[fn] < 49) ? __expf(val[fn] - mx) : 0.f;
        sum += e[fn];
      }
      #pragma unroll
      for (int off = 1; off < 16; off <<= 1) sum += __shfl_xor(sum, off);
      const float inv = 1.f / sum;
      const int yi = r / 7, xi = r % 7;
      #pragma unroll
      for (int fn = 0; fn < 4; ++fn) {
        float a = 0.f;
        if (r < 49 && colv[fn] < 49) {
          const int c = colv[fn];
          const int idx = (yi - c / 7 + 6) * 13 + (xi - c % 7 + 6);
          a = e[fn] * inv + bias_table[idx * NHEADS + head];
        }
        Ps[r * 64 + colv[fn]] = f2bf(a);
      }
    }
  }
  __syncthreads();

  // O = P @ V  (64x32, K=64)
  f32x4 o[4][2] = {};
  #pragma unroll
  for (int kk = 0; kk < 64; kk += 32) {
    bhalf8 pf[4], vf[2];
    #pragma unroll
    for (int f = 0; f < 4; ++f)
      pf[f] = *(const bhalf8*)&Ps[(f * 16 + l15) * 64 + kk + l16 * 8];
    #pragma unroll
    for (int f = 0; f < 2; ++f)
      vf[f] = *(const bhalf8*)&Vt[(f * 16 + l15) * 64 + kk + l16 * 8];
    #pragma unroll
    for (int fm = 0; fm < 4; ++fm)
      #pragma unroll
      for (int fn = 0; fn < 2; ++fn)
        o[fm][fn] = __builtin_amdgcn_mfma_f32_16x16x32_bf16(pf[fm], vf[fn], o[fm][fn], 0, 0, 0);
  }

  #pragma unroll
  for (int fm = 0; fm < 4; ++fm) {
    #pragma unroll
    for (int i = 0; i < 4; ++i) {
      const int r = fm * 16 + l16 * 4 + i;
      if (r < 49) {
        const int grow = b * 3136 + (wi * 7 + r / 7) * 56 + (wj * 7 + r % 7);
        #pragma unroll
        for (int fn = 0; fn < 2; ++fn) {
          const int d = fn * 16 + l15;
          attn_out[(size_t)grow * HID + head * HDIM + d] = f2bf(o[fm][fn][i]);
        }
      }
    }
  }
}

extern "C" void kernel_launch(void* const* d_in, const int* in_sizes, int n_in,
                              void* d_out, int out_size, void* d_ws, size_t ws_size,
                              hipStream_t stream) {
  const float* x          = (const float*)d_in[0];
  const float* w_qkv      = (const float*)d_in[1];
  const float* w_out      = (const float*)d_in[2];
  const float* b_out      = (const float*)d_in[3];
  const float* bias_table = (const float*)d_in[4];
  float* out = (float*)d_out;

  ushort* qkv    = (ushort*)d_ws;                       // [TOK][1152] bf16
  ushort* attn_o = qkv + (size_t)TOK * NQKV;            // [TOK][384]  bf16

  // 1) qkv = x @ w_qkv   (M=100352, N=1152, K=384)
  gemm_mfma<false, false><<<dim3(NQKV / 128, TOK / 128), dim3(256), 0, stream>>>(
      x, w_qkv, nullptr, qkv, TOK, NQKV, HID);

  // 2) window attention per (window, head)
  win_attn<<<dim3(2048 * NHEADS), dim3(64), 0, stream>>>(qkv, bias_table, attn_o);

  // 3) out = attn_o @ w_out + b_out  (M=100352, N=384, K=384), fp32 out
  gemm_mfma<true, true><<<dim3(HID / 128, TOK / 128), dim3(256), 0, stream>>>(
      attn_o, w_out, b_out, out, TOK, HID, HID);
}

// Round 2
// 454.787 us; speedup vs baseline: 1.2639x; 1.2639x over previous
//
#include <hip/hip_runtime.h>
#include <hip/hip_bf16.h>
#include <cstdint>

#define TOK 100352
#define HID 384
#define NQKV 1152
#define NHEADS 12
#define HDIM 32

typedef __attribute__((ext_vector_type(8))) short bhalf8;
typedef __attribute__((ext_vector_type(4))) float f32x4;

__device__ __forceinline__ ushort f2bf(float f) {
  uint32_t u = __float_as_uint(f);
  return (ushort)((u + 0x7FFFu + ((u >> 16) & 1u)) >> 16);
}

__device__ __forceinline__ void gload_lds16(const ushort* g, ushort* l) {
  __builtin_amdgcn_global_load_lds(
      (const __attribute__((address_space(1))) unsigned int*)g,
      (__attribute__((address_space(3))) unsigned int*)l, 16, 0, 0);
}

// ---- pre-pass: fp32 -> bf16, vectorized 8/thread ----
__global__ __launch_bounds__(256)
void cvt_bf16(const float* __restrict__ in, ushort* __restrict__ out, const int n8) {
  const int i = blockIdx.x * 256 + threadIdx.x;
  if (i >= n8) return;
  const float4 f0 = ((const float4*)in)[(size_t)i * 2];
  const float4 f1 = ((const float4*)in)[(size_t)i * 2 + 1];
  bhalf8 v;
  v[0] = (short)f2bf(f0.x); v[1] = (short)f2bf(f0.y);
  v[2] = (short)f2bf(f0.z); v[3] = (short)f2bf(f0.w);
  v[4] = (short)f2bf(f1.x); v[5] = (short)f2bf(f1.y);
  v[6] = (short)f2bf(f1.z); v[7] = (short)f2bf(f1.w);
  ((bhalf8*)out)[i] = v;
}

// ---- pre-pass: [R][C] fp32 -> [C][R] bf16 (tiny weights) ----
__global__ __launch_bounds__(256)
void transpose_cvt(const float* __restrict__ in, ushort* __restrict__ out,
                   const int R, const int C) {
  const int i = blockIdx.x * 256 + threadIdx.x;
  if (i >= R * C) return;
  const int r = i % R, c = i / R;
  out[i] = f2bf(in[(size_t)r * C + c]);
}

// ---- m97-structure GEMM: C = A[M][K] @ Bt[N][K]^T, bf16 in, fp32 accum ----
template<bool OUT_F32_BIAS>
__global__ __launch_bounds__(256)
void gemm_bt(const ushort* __restrict__ A, const ushort* __restrict__ Bt,
             const float* __restrict__ bias, void* __restrict__ Cp,
             const int N, const int K, const int nbx)
{
  __shared__ ushort As[128 * 64];  // [m][k] linear (gload_lds dest)
  __shared__ ushort Bs[128 * 64];  // [n][k] linear

  const int tid = threadIdx.x;
  const int lane = tid & 63;
  const int wave = tid >> 6;
  const int wm = wave >> 1, wn = wave & 1;
  const int l15 = lane & 15, l16 = lane >> 4;

  // XCD-aware swizzle (T1): consecutive logical tiles -> same XCD L2
  int bid = blockIdx.x;
  const int nwg = gridDim.x;
  if ((nwg & 7) == 0) bid = (bid & 7) * (nwg >> 3) + (bid >> 3);
  const int row0 = (bid / nbx) * 128;
  const int col0 = (bid % nbx) * 128;

  f32x4 acc[4][4] = {};

  for (int ko = 0; ko < K; ko += 64) {
    if (ko) __syncthreads();
    // stage A,B tiles (128x64 bf16 each) via direct global->LDS, 16B/lane
    #pragma unroll
    for (int it = 0; it < 4; ++it) {
      const int chunk = it * 4 + wave;        // 0..15
      const int idx = chunk * 64 + lane;      // 0..1023, covers 8 elems each
      const int m = idx >> 3;
      const int k8 = (idx & 7) * 8;
      gload_lds16(A + (size_t)(row0 + m) * K + ko + k8, &As[chunk * 512]);
      gload_lds16(Bt + (size_t)(col0 + m) * K + ko + k8, &Bs[chunk * 512]);
    }
    __syncthreads();
    #pragma unroll
    for (int kk = 0; kk < 64; kk += 32) {
      bhalf8 af[4], bfr[4];
      #pragma unroll
      for (int f = 0; f < 4; ++f) {
        af[f] = *(const bhalf8*)&As[(wm * 64 + f * 16 + l15) * 64 + kk + l16 * 8];
        bfr[f] = *(const bhalf8*)&Bs[(wn * 64 + f * 16 + l15) * 64 + kk + l16 * 8];
      }
      #pragma unroll
      for (int fm = 0; fm < 4; ++fm)
        #pragma unroll
        for (int fn = 0; fn < 4; ++fn)
          acc[fm][fn] = __builtin_amdgcn_mfma_f32_16x16x32_bf16(af[fm], bfr[fn], acc[fm][fn], 0, 0, 0);
    }
  }

  // epilogue: D row=(lane>>4)*4+i, col=lane&15
  #pragma unroll
  for (int fm = 0; fm < 4; ++fm) {
    const int rb = row0 + wm * 64 + fm * 16 + l16 * 4;
    #pragma unroll
    for (int fn = 0; fn < 4; ++fn) {
      const int cc = col0 + wn * 64 + fn * 16 + l15;
      const float badd = OUT_F32_BIAS ? bias[cc] : 0.f;
      #pragma unroll
      for (int i = 0; i < 4; ++i) {
        const float vv = acc[fm][fn][i] + badd;
        if (OUT_F32_BIAS) ((float*)Cp)[(size_t)(rb + i) * N + cc] = vv;
        else ((ushort*)Cp)[(size_t)(rb + i) * N + cc] = f2bf(vv);
      }
    }
  }
}

// ---- window attention: one wave per (window, head), 49 tokens padded to 64 ----
__global__ __launch_bounds__(64)
void win_attn(const ushort* __restrict__ qkv, const float* __restrict__ bias_table,
              ushort* __restrict__ attn_out)
{
  __shared__ ushort Qs[64 * 32];
  __shared__ ushort Ks[64 * 32];
  __shared__ ushort Vt[32 * 64];  // [d][token]
  __shared__ ushort Ps[64 * 64];

  const int lane = threadIdx.x;
  const int l15 = lane & 15, l16 = lane >> 4;
  const int bid = blockIdx.x;
  const int head = bid % NHEADS;
  const int win = bid / NHEADS;
  const int b  = win >> 6;
  const int wi = (win >> 3) & 7;
  const int wj = win & 7;

  {
    const bhalf8 z = {0,0,0,0,0,0,0,0};
    #pragma unroll
    for (int i = 0; i < 4; ++i) {
      ((bhalf8*)Qs)[lane + 64 * i] = z;
      ((bhalf8*)Ks)[lane + 64 * i] = z;
      ((bhalf8*)Vt)[lane + 64 * i] = z;
    }
  }
  __syncthreads();

  if (lane < 49) {
    const int grow = b * 3136 + (wi * 7 + lane / 7) * 56 + (wj * 7 + lane % 7);
    const ushort* base = qkv + (size_t)grow * NQKV + head * HDIM;
    #pragma unroll
    for (int c2 = 0; c2 < 4; ++c2) {
      *(bhalf8*)&Qs[lane * 32 + c2 * 8] = *(const bhalf8*)(base + c2 * 8);
      *(bhalf8*)&Ks[lane * 32 + c2 * 8] = *(const bhalf8*)(base + 384 + c2 * 8);
    }
    #pragma unroll
    for (int d = 0; d < 32; ++d) Vt[d * 64 + lane] = base[768 + d];
  }
  __syncthreads();

  // S = Q @ K^T  (64x64, K=32)
  bhalf8 qf[4], kf[4];
  #pragma unroll
  for (int f = 0; f < 4; ++f) {
    qf[f] = *(const bhalf8*)&Qs[(f * 16 + l15) * 32 + l16 * 8];
    kf[f] = *(const bhalf8*)&Ks[(f * 16 + l15) * 32 + l16 * 8];
  }
  const f32x4 fz = {};
  f32x4 s[4][4];
  #pragma unroll
  for (int fm = 0; fm < 4; ++fm)
    #pragma unroll
    for (int fn = 0; fn < 4; ++fn)
      s[fm][fn] = __builtin_amdgcn_mfma_f32_16x16x32_bf16(qf[fm], kf[fn], fz, 0, 0, 0);

  const float scale = 0.17677669529663687f; // 32^-0.5
  const int colv[4] = {l15, 16 + l15, 32 + l15, 48 + l15};

  #pragma unroll
  for (int fm = 0; fm < 4; ++fm) {
    #pragma unroll
    for (int i = 0; i < 4; ++i) {
      const int r = fm * 16 + l16 * 4 + i;
      float val[4];
      float mx = -1e30f;
      #pragma unroll
      for (int fn = 0; fn < 4; ++fn) {
        val[fn] = s[fm][fn][i] * scale;
        if (colv[fn] < 49) mx = fmaxf(mx, val[fn]);
      }
      #pragma unroll
      for (int off = 1; off < 16; off <<= 1) mx = fmaxf(mx, __shfl_xor(mx, off));
      float e[4]; float sum = 0.f;
      #pragma unroll
      for (int fn = 0; fn < 4; ++fn) {
        e[fn] = (colv[fn] < 49) ? __expf(val[fn] - mx) : 0.f;
        sum += e[fn];
      }
      #pragma unroll
      for (int off = 1; off < 16; off <<= 1) sum += __shfl_xor(sum, off);
      const float inv = 1.f / sum;
      const int yi = r / 7, xi = r % 7;
      #pragma unroll
      for (int fn = 0; fn < 4; ++fn) {
        float a = 0.f;
        if (r < 49 && colv[fn] < 49) {
          const int c = colv[fn];
          const int idx = (yi - c / 7 + 6) * 13 + (xi - c % 7 + 6);
          a = e[fn] * inv + bias_table[idx * NHEADS + head];
        }
        Ps[r * 64 + colv[fn]] = f2bf(a);
      }
    }
  }
  __syncthreads();

  // O = P @ V  (64x32, K=64)
  f32x4 o[4][2] = {};
  #pragma unroll
  for (int kk = 0; kk < 64; kk += 32) {
    bhalf8 pf[4], vf[2];
    #pragma unroll
    for (int f = 0; f < 4; ++f)
      pf[f] = *(const bhalf8*)&Ps[(f * 16 + l15) * 64 + kk + l16 * 8];
    #pragma unroll
    for (int f = 0; f < 2; ++f)
      vf[f] = *(const bhalf8*)&Vt[(f * 16 + l15) * 64 + kk + l16 * 8];
    #pragma unroll
    for (int fm = 0; fm < 4; ++fm)
      #pragma unroll
      for (int fn = 0; fn < 2; ++fn)
        o[fm][fn] = __builtin_amdgcn_mfma_f32_16x16x32_bf16(pf[fm], vf[fn], o[fm][fn], 0, 0, 0);
  }

  #pragma unroll
  for (int fm = 0; fm < 4; ++fm) {
    #pragma unroll
    for (int i = 0; i < 4; ++i) {
      const int r = fm * 16 + l16 * 4 + i;
      if (r < 49) {
        const int grow = b * 3136 + (wi * 7 + r / 7) * 56 + (wj * 7 + r % 7);
        #pragma unroll
        for (int fn = 0; fn < 2; ++fn) {
          const int d = fn * 16 + l15;
          attn_out[(size_t)grow * HID + head * HDIM + d] = f2bf(o[fm][fn][i]);
        }
      }
    }
  }
}

extern "C" void kernel_launch(void* const* d_in, const int* in_sizes, int n_in,
                              void* d_out, int out_size, void* d_ws, size_t ws_size,
                              hipStream_t stream) {
  const float* x          = (const float*)d_in[0];
  const float* w_qkv      = (const float*)d_in[1];
  const float* w_out      = (const float*)d_in[2];
  const float* b_out      = (const float*)d_in[3];
  const float* bias_table = (const float*)d_in[4];
  float* out = (float*)d_out;

  // ws layout (ushorts): xb | qkv | wqkvT | woutT ; attn_o aliases xb
  ushort* xb     = (ushort*)d_ws;                       // [TOK][384]  bf16
  ushort* qkv    = xb + (size_t)TOK * HID;              // [TOK][1152] bf16
  ushort* wqkvT  = qkv + (size_t)TOK * NQKV;            // [1152][384] bf16
  ushort* woutT  = wqkvT + (size_t)NQKV * HID;          // [384][384]  bf16
  ushort* attn_o = xb;                                  // alias (xb dead after GEMM1)

  // 0) conversions
  {
    const int n8 = TOK * HID / 8;
    cvt_bf16<<<dim3((n8 + 255) / 256), dim3(256), 0, stream>>>(x, xb, n8);
    transpose_cvt<<<dim3(HID * NQKV / 256), dim3(256), 0, stream>>>(w_qkv, wqkvT, HID, NQKV);
    transpose_cvt<<<dim3(HID * HID / 256), dim3(256), 0, stream>>>(w_out, woutT, HID, HID);
  }

  // 1) qkv = xb @ wqkvT^T   (M=100352, N=1152, K=384)
  gemm_bt<false><<<dim3((NQKV / 128) * (TOK / 128)), dim3(256), 0, stream>>>(
      xb, wqkvT, nullptr, qkv, NQKV, HID, NQKV / 128);

  // 2) window attention per (window, head)
  win_attn<<<dim3(2048 * NHEADS), dim3(64), 0, stream>>>(qkv, bias_table, attn_o);

  // 3) out = attn_o @ woutT^T + b_out  (M=100352, N=384, K=384), fp32 out
  gemm_bt<true><<<dim3((HID / 128) * (TOK / 128)), dim3(256), 0, stream>>>(
      attn_o, woutT, b_out, out, HID, HID, HID / 128);
}

// Round 3
// 363.906 us; speedup vs baseline: 1.5795x; 1.2497x over previous
//
#include <hip/hip_runtime.h>
#include <hip/hip_bf16.h>
#include <cstdint>

#define TOK 100352
#define HID 384
#define NQKV 1152
#define NHEADS 12
#define HDIM 32

typedef __attribute__((ext_vector_type(8))) short bhalf8;
typedef __attribute__((ext_vector_type(4))) float f32x4;

__device__ __forceinline__ ushort f2bf(float f) {
  uint32_t u = __float_as_uint(f);
  return (ushort)((u + 0x7FFFu + ((u >> 16) & 1u)) >> 16);
}

__device__ __forceinline__ void gload_lds16(const ushort* g, ushort* l) {
  __builtin_amdgcn_global_load_lds(
      (const __attribute__((address_space(1))) unsigned int*)g,
      (__attribute__((address_space(3))) unsigned int*)l, 16, 0, 0);
}

// ---- pre-pass: fp32 -> bf16, vectorized 8/thread ----
__global__ __launch_bounds__(256)
void cvt_bf16(const float* __restrict__ in, ushort* __restrict__ out, const int n8) {
  const int i = blockIdx.x * 256 + threadIdx.x;
  if (i >= n8) return;
  const float4 f0 = ((const float4*)in)[(size_t)i * 2];
  const float4 f1 = ((const float4*)in)[(size_t)i * 2 + 1];
  bhalf8 v;
  v[0] = (short)f2bf(f0.x); v[1] = (short)f2bf(f0.y);
  v[2] = (short)f2bf(f0.z); v[3] = (short)f2bf(f0.w);
  v[4] = (short)f2bf(f1.x); v[5] = (short)f2bf(f1.y);
  v[6] = (short)f2bf(f1.z); v[7] = (short)f2bf(f1.w);
  ((bhalf8*)out)[i] = v;
}

// ---- pre-pass: [R][C] fp32 -> [C][R] bf16 (tiny weights) ----
__global__ __launch_bounds__(256)
void transpose_cvt(const float* __restrict__ in, ushort* __restrict__ out,
                   const int R, const int C) {
  const int i = blockIdx.x * 256 + threadIdx.x;
  if (i >= R * C) return;
  const int r = i % R, c = i / R;
  out[i] = f2bf(in[(size_t)r * C + c]);
}

// ---- pre-pass: expand rel-pos bias to [head][49][49] f32 ----
__global__ __launch_bounds__(256)
void expand_bias(const float* __restrict__ bt, float* __restrict__ bx) {
  const int i = blockIdx.x * 256 + threadIdx.x;
  if (i >= NHEADS * 49 * 49) return;
  const int head = i / 2401, rc = i % 2401, r = rc / 49, c = rc % 49;
  const int idx = (r / 7 - c / 7 + 6) * 13 + (r % 7 - c % 7 + 6);
  bx[i] = bt[idx * NHEADS + head];
}

// ---- m97-structure GEMM: C = A[M][K] @ Bt[N][K]^T, bf16 in, fp32 accum ----
template<bool OUT_F32_BIAS>
__global__ __launch_bounds__(256)
void gemm_bt(const ushort* __restrict__ A, const ushort* __restrict__ Bt,
             const float* __restrict__ bias, void* __restrict__ Cp,
             const int N, const int K, const int nbx)
{
  __shared__ ushort As[128 * 64];
  __shared__ ushort Bs[128 * 64];

  const int tid = threadIdx.x;
  const int lane = tid & 63;
  const int wave = tid >> 6;
  const int wm = wave >> 1, wn = wave & 1;
  const int l15 = lane & 15, l16 = lane >> 4;

  int bid = blockIdx.x;
  const int nwg = gridDim.x;
  if ((nwg & 7) == 0) bid = (bid & 7) * (nwg >> 3) + (bid >> 3);
  const int row0 = (bid / nbx) * 128;
  const int col0 = (bid % nbx) * 128;

  f32x4 acc[4][4] = {};

  for (int ko = 0; ko < K; ko += 64) {
    if (ko) __syncthreads();
    #pragma unroll
    for (int it = 0; it < 4; ++it) {
      const int chunk = it * 4 + wave;
      const int idx = chunk * 64 + lane;
      const int m = idx >> 3;
      const int k8 = (idx & 7) * 8;
      gload_lds16(A + (size_t)(row0 + m) * K + ko + k8, &As[chunk * 512]);
      gload_lds16(Bt + (size_t)(col0 + m) * K + ko + k8, &Bs[chunk * 512]);
    }
    __syncthreads();
    #pragma unroll
    for (int kk = 0; kk < 64; kk += 32) {
      bhalf8 af[4], bfr[4];
      #pragma unroll
      for (int f = 0; f < 4; ++f) {
        af[f] = *(const bhalf8*)&As[(wm * 64 + f * 16 + l15) * 64 + kk + l16 * 8];
        bfr[f] = *(const bhalf8*)&Bs[(wn * 64 + f * 16 + l15) * 64 + kk + l16 * 8];
      }
      #pragma unroll
      for (int fm = 0; fm < 4; ++fm)
        #pragma unroll
        for (int fn = 0; fn < 4; ++fn)
          acc[fm][fn] = __builtin_amdgcn_mfma_f32_16x16x32_bf16(af[fm], bfr[fn], acc[fm][fn], 0, 0, 0);
    }
  }

  #pragma unroll
  for (int fm = 0; fm < 4; ++fm) {
    const int rb = row0 + wm * 64 + fm * 16 + l16 * 4;
    #pragma unroll
    for (int fn = 0; fn < 4; ++fn) {
      const int cc = col0 + wn * 64 + fn * 16 + l15;
      const float badd = OUT_F32_BIAS ? bias[cc] : 0.f;
      #pragma unroll
      for (int i = 0; i < 4; ++i) {
        const float vv = acc[fm][fn][i] + badd;
        if (OUT_F32_BIAS) ((float*)Cp)[(size_t)(rb + i) * N + cc] = vv;
        else ((ushort*)Cp)[(size_t)(rb + i) * N + cc] = f2bf(vv);
      }
    }
  }
}

// ---- window attention v2: 4 waves/block, wave = one (window, head) ----
// Q/K fragments direct from global; V via coalesced load + swizzled LDS
// transpose; P via swizzled LDS round-trip; no barriers (per-wave LDS).
__global__ __launch_bounds__(256)
void win_attn2(const ushort* __restrict__ qkv, const float* __restrict__ biasx,
               ushort* __restrict__ attn_out)
{
  __shared__ ushort VtAll[4][32 * 64];   // [d][t] swizzled
  __shared__ ushort PsAll[4][64 * 64];   // [r][c] swizzled

  const int tid = threadIdx.x;
  const int lane = tid & 63, wave = tid >> 6;
  const int l15 = lane & 15, l16 = lane >> 4;
  const int gid = blockIdx.x * 4 + wave;
  const int head = gid % NHEADS;
  const int win = gid / NHEADS;
  const int b = win >> 6, wi = (win >> 3) & 7, wj = win & 7;
  char* Vt = (char*)VtAll[wave];
  char* Ps = (char*)PsAll[wave];

  const int base_row = b * 3136 + wi * 7 * 56 + wj * 7;

  // ---- V stage: coalesced 16B loads, swizzled transposed LDS writes ----
  #pragma unroll
  for (int it = 0; it < 4; ++it) {
    const int t = lane;
    const int d0 = it * 8;
    bhalf8 v = {0, 0, 0, 0, 0, 0, 0, 0};
    if (t < 49) {
      const size_t off = (size_t)(base_row + (t / 7) * 56 + (t % 7)) * NQKV
                         + 768 + head * HDIM + d0;
      v = *(const bhalf8*)(qkv + off);
    }
    #pragma unroll
    for (int j = 0; j < 8; ++j) {
      const int d = d0 + j;
      const int byteoff = ((d * 64 + t) * 2) ^ ((d & 7) << 4);
      *(ushort*)(Vt + byteoff) = (ushort)v[j];
    }
  }

  // ---- Q/K fragments direct from global ----
  bhalf8 qf[4], kf[4];
  #pragma unroll
  for (int f = 0; f < 4; ++f) {
    const int r = f * 16 + l15;
    const int rr = r < 49 ? r : 48;
    const size_t off = (size_t)(base_row + (rr / 7) * 56 + (rr % 7)) * NQKV
                       + head * HDIM + l16 * 8;
    qf[f] = *(const bhalf8*)(qkv + off);
    kf[f] = *(const bhalf8*)(qkv + off + 384);
  }

  // ---- S = Q @ K^T ----
  const f32x4 fz = {};
  f32x4 s[4][4];
  #pragma unroll
  for (int fm = 0; fm < 4; ++fm)
    #pragma unroll
    for (int fn = 0; fn < 4; ++fn)
      s[fm][fn] = __builtin_amdgcn_mfma_f32_16x16x32_bf16(qf[fm], kf[fn], fz, 0, 0, 0);

  // ---- softmax (16-lane groups per row), bias added AFTER softmax ----
  const float scale = 0.17677669529663687f;
  const int colv[4] = {l15, 16 + l15, 32 + l15, 48 + l15};
  const float* brow_base = biasx + (size_t)head * 2401;

  #pragma unroll
  for (int fm = 0; fm < 4; ++fm) {
    #pragma unroll
    for (int i = 0; i < 4; ++i) {
      const int r = fm * 16 + l16 * 4 + i;
      float val[4];
      float mx = -1e30f;
      #pragma unroll
      for (int fn = 0; fn < 4; ++fn) {
        val[fn] = s[fm][fn][i] * scale;
        if (colv[fn] < 49) mx = fmaxf(mx, val[fn]);
      }
      #pragma unroll
      for (int off = 1; off < 16; off <<= 1) mx = fmaxf(mx, __shfl_xor(mx, off));
      float e[4]; float sum = 0.f;
      #pragma unroll
      for (int fn = 0; fn < 4; ++fn) {
        e[fn] = (colv[fn] < 49) ? __expf(val[fn] - mx) : 0.f;
        sum += e[fn];
      }
      #pragma unroll
      for (int off = 1; off < 16; off <<= 1) sum += __shfl_xor(sum, off);
      const float inv = 1.f / sum;
      const float* brow = brow_base + r * 49;
      #pragma unroll
      for (int fn = 0; fn < 4; ++fn) {
        const int c = colv[fn];
        float a = 0.f;
        if (r < 49 && c < 49) a = e[fn] * inv + brow[c];
        const int byteoff = ((r * 64 + c) * 2) ^ ((r & 7) << 4);
        *(ushort*)(Ps + byteoff) = f2bf(a);
      }
    }
  }

  // ---- O = P @ V ----
  f32x4 o[4][2] = {};
  #pragma unroll
  for (int kk = 0; kk < 64; kk += 32) {
    bhalf8 pf[4], vf[2];
    #pragma unroll
    for (int f = 0; f < 4; ++f) {
      const int r = f * 16 + l15;
      pf[f] = *(const bhalf8*)(Ps + (((r * 64 + kk + l16 * 8) * 2) ^ ((r & 7) << 4)));
    }
    #pragma unroll
    for (int f = 0; f < 2; ++f) {
      const int d = f * 16 + l15;
      vf[f] = *(const bhalf8*)(Vt + (((d * 64 + kk + l16 * 8) * 2) ^ ((d & 7) << 4)));
    }
    #pragma unroll
    for (int fm = 0; fm < 4; ++fm)
      #pragma unroll
      for (int fn = 0; fn < 2; ++fn)
        o[fm][fn] = __builtin_amdgcn_mfma_f32_16x16x32_bf16(pf[fm], vf[fn], o[fm][fn], 0, 0, 0);
  }

  // ---- store O ----
  #pragma unroll
  for (int fm = 0; fm < 4; ++fm) {
    #pragma unroll
    for (int i = 0; i < 4; ++i) {
      const int r = fm * 16 + l16 * 4 + i;
      if (r < 49) {
        const int grow = base_row + (r / 7) * 56 + (r % 7);
        #pragma unroll
        for (int fn = 0; fn < 2; ++fn) {
          const int d = fn * 16 + l15;
          attn_out[(size_t)grow * HID + head * HDIM + d] = f2bf(o[fm][fn][i]);
        }
      }
    }
  }
}

extern "C" void kernel_launch(void* const* d_in, const int* in_sizes, int n_in,
                              void* d_out, int out_size, void* d_ws, size_t ws_size,
                              hipStream_t stream) {
  const float* x          = (const float*)d_in[0];
  const float* w_qkv      = (const float*)d_in[1];
  const float* w_out      = (const float*)d_in[2];
  const float* b_out      = (const float*)d_in[3];
  const float* bias_table = (const float*)d_in[4];
  float* out = (float*)d_out;

  // ws layout (ushorts): xb | qkv | wqkvT | woutT | biasx(f32)
  ushort* xb     = (ushort*)d_ws;                       // [TOK][384]  bf16
  ushort* qkv    = xb + (size_t)TOK * HID;              // [TOK][1152] bf16
  ushort* wqkvT  = qkv + (size_t)TOK * NQKV;            // [1152][384] bf16
  ushort* woutT  = wqkvT + (size_t)NQKV * HID;          // [384][384]  bf16
  float*  biasx  = (float*)(woutT + (size_t)HID * HID); // [12][49][49] f32
  ushort* attn_o = xb;                                  // alias (xb dead after GEMM1)

  // 0) conversions
  {
    const int n8 = TOK * HID / 8;
    cvt_bf16<<<dim3((n8 + 255) / 256), dim3(256), 0, stream>>>(x, xb, n8);
    transpose_cvt<<<dim3(HID * NQKV / 256), dim3(256), 0, stream>>>(w_qkv, wqkvT, HID, NQKV);
    transpose_cvt<<<dim3(HID * HID / 256), dim3(256), 0, stream>>>(w_out, woutT, HID, HID);
    expand_bias<<<dim3((NHEADS * 2401 + 255) / 256), dim3(256), 0, stream>>>(bias_table, biasx);
  }

  // 1) qkv = xb @ wqkvT^T   (M=100352, N=1152, K=384)
  gemm_bt<false><<<dim3((NQKV / 128) * (TOK / 128)), dim3(256), 0, stream>>>(
      xb, wqkvT, nullptr, qkv, NQKV, HID, NQKV / 128);

  // 2) window attention: 4 waves/block, one (window, head) per wave
  win_attn2<<<dim3(2048 * NHEADS / 4), dim3(256), 0, stream>>>(qkv, biasx, attn_o);

  // 3) out = attn_o @ woutT^T + b_out  (M=100352, N=384, K=384), fp32 out
  gemm_bt<true><<<dim3((HID / 128) * (TOK / 128)), dim3(256), 0, stream>>>(
      attn_o, woutT, b_out, out, HID, HID, HID / 128);
}

// Round 4
// 358.887 us; speedup vs baseline: 1.6016x; 1.0140x over previous
//
#include <hip/hip_runtime.h>
#include <hip/hip_bf16.h>
#include <cstdint>

#define TOK 100352
#define HID 384
#define NQKV 1152
#define NHEADS 12
#define HDIM 32

typedef __attribute__((ext_vector_type(8))) short bhalf8;
typedef __attribute__((ext_vector_type(4))) float f32x4;

__device__ __forceinline__ ushort f2bf(float f) {
  uint32_t u = __float_as_uint(f);
  return (ushort)((u + 0x7FFFu + ((u >> 16) & 1u)) >> 16);
}

__device__ __forceinline__ void gload_lds16(const ushort* g, ushort* l) {
  __builtin_amdgcn_global_load_lds(
      (const __attribute__((address_space(1))) unsigned int*)g,
      (__attribute__((address_space(3))) unsigned int*)l, 16, 0, 0);
}

// ---- pre-pass: fp32 -> bf16, vectorized 8/thread ----
__global__ __launch_bounds__(256)
void cvt_bf16(const float* __restrict__ in, ushort* __restrict__ out, const int n8) {
  const int i = blockIdx.x * 256 + threadIdx.x;
  if (i >= n8) return;
  const float4 f0 = ((const float4*)in)[(size_t)i * 2];
  const float4 f1 = ((const float4*)in)[(size_t)i * 2 + 1];
  bhalf8 v;
  v[0] = (short)f2bf(f0.x); v[1] = (short)f2bf(f0.y);
  v[2] = (short)f2bf(f0.z); v[3] = (short)f2bf(f0.w);
  v[4] = (short)f2bf(f1.x); v[5] = (short)f2bf(f1.y);
  v[6] = (short)f2bf(f1.z); v[7] = (short)f2bf(f1.w);
  ((bhalf8*)out)[i] = v;
}

// ---- pre-pass: [R][C] fp32 -> [C][R] bf16 (tiny weights) ----
__global__ __launch_bounds__(256)
void transpose_cvt(const float* __restrict__ in, ushort* __restrict__ out,
                   const int R, const int C) {
  const int i = blockIdx.x * 256 + threadIdx.x;
  if (i >= R * C) return;
  const int r = i % R, c = i / R;
  out[i] = f2bf(in[(size_t)r * C + c]);
}

// ---- pre-pass: expand rel-pos bias to [head][49][49] f32 ----
__global__ __launch_bounds__(256)
void expand_bias(const float* __restrict__ bt, float* __restrict__ bx) {
  const int i = blockIdx.x * 256 + threadIdx.x;
  if (i >= NHEADS * 49 * 49) return;
  const int head = i / 2401, rc = i % 2401, r = rc / 49, c = rc % 49;
  const int idx = (r / 7 - c / 7 + 6) * 13 + (r % 7 - c % 7 + 6);
  bx[i] = bt[idx * NHEADS + head];
}

// ---- m97-structure GEMM + T2 swizzle: C = A[M][K] @ Bt[N][K]^T ----
// LDS written LINEARLY by global_load_lds; swizzle achieved by XORing the
// GLOBAL source k-offset (k8 ^= row&7) and the LDS READ address (rule #21:
// source perm and read perm are the same involution).
template<bool OUT_F32_BIAS>
__global__ __launch_bounds__(256)
void gemm_bt(const ushort* __restrict__ A, const ushort* __restrict__ Bt,
             const float* __restrict__ bias, void* __restrict__ Cp,
             const int N, const int K, const int nbx)
{
  __shared__ ushort As[128 * 64];
  __shared__ ushort Bs[128 * 64];

  const int tid = threadIdx.x;
  const int lane = tid & 63;
  const int wave = tid >> 6;
  const int wm = wave >> 1, wn = wave & 1;
  const int l15 = lane & 15, l16 = lane >> 4;

  int bid = blockIdx.x;
  const int nwg = gridDim.x;
  if ((nwg & 7) == 0) bid = (bid & 7) * (nwg >> 3) + (bid >> 3);
  const int row0 = (bid / nbx) * 128;
  const int col0 = (bid % nbx) * 128;

  f32x4 acc[4][4] = {};

  for (int ko = 0; ko < K; ko += 64) {
    if (ko) __syncthreads();
    #pragma unroll
    for (int it = 0; it < 4; ++it) {
      const int chunk = it * 4 + wave;
      const int idx = chunk * 64 + lane;
      const int m = idx >> 3;                           // tile row 0..127
      const int k8 = (((idx & 7) ^ (m & 7)) * 8);       // inverse-swizzled source k
      gload_lds16(A + (size_t)(row0 + m) * K + ko + k8, &As[chunk * 512]);
      gload_lds16(Bt + (size_t)(col0 + m) * K + ko + k8, &Bs[chunk * 512]);
    }
    __syncthreads();
    #pragma unroll
    for (int kk = 0; kk < 64; kk += 32) {
      bhalf8 af[4], bfr[4];
      #pragma unroll
      for (int f = 0; f < 4; ++f) {
        const int ra = wm * 64 + f * 16 + l15;
        const int rb = wn * 64 + f * 16 + l15;
        const int kb = (kk + l16 * 8) * 2;
        af[f]  = *(const bhalf8*)((const char*)As + ra * 128 + (kb ^ ((ra & 7) << 4)));
        bfr[f] = *(const bhalf8*)((const char*)Bs + rb * 128 + (kb ^ ((rb & 7) << 4)));
      }
      #pragma unroll
      for (int fm = 0; fm < 4; ++fm)
        #pragma unroll
        for (int fn = 0; fn < 4; ++fn)
          acc[fm][fn] = __builtin_amdgcn_mfma_f32_16x16x32_bf16(af[fm], bfr[fn], acc[fm][fn], 0, 0, 0);
    }
  }

  #pragma unroll
  for (int fm = 0; fm < 4; ++fm) {
    const int rb = row0 + wm * 64 + fm * 16 + l16 * 4;
    #pragma unroll
    for (int fn = 0; fn < 4; ++fn) {
      const int cc = col0 + wn * 64 + fn * 16 + l15;
      const float badd = OUT_F32_BIAS ? bias[cc] : 0.f;
      #pragma unroll
      for (int i = 0; i < 4; ++i) {
        const float vv = acc[fm][fn][i] + badd;
        if (OUT_F32_BIAS) ((float*)Cp)[(size_t)(rb + i) * N + cc] = vv;
        else ((ushort*)Cp)[(size_t)(rb + i) * N + cc] = f2bf(vv);
      }
    }
  }
}

// ---- window attention v2: 4 waves/block, wave = one (window, head) ----
__global__ __launch_bounds__(256)
void win_attn2(const ushort* __restrict__ qkv, const float* __restrict__ biasx,
               ushort* __restrict__ attn_out)
{
  __shared__ ushort VtAll[4][32 * 64];   // [d][t] swizzled
  __shared__ ushort PsAll[4][64 * 64];   // [r][c] swizzled

  const int tid = threadIdx.x;
  const int lane = tid & 63, wave = tid >> 6;
  const int l15 = lane & 15, l16 = lane >> 4;
  const int gid = blockIdx.x * 4 + wave;
  const int head = gid % NHEADS;
  const int win = gid / NHEADS;
  const int b = win >> 6, wi = (win >> 3) & 7, wj = win & 7;
  char* Vt = (char*)VtAll[wave];
  char* Ps = (char*)PsAll[wave];

  const int base_row = b * 3136 + wi * 7 * 56 + wj * 7;

  // ---- V stage: coalesced 16B loads, swizzled transposed LDS writes ----
  #pragma unroll
  for (int it = 0; it < 4; ++it) {
    const int t = lane;
    const int d0 = it * 8;
    bhalf8 v = {0, 0, 0, 0, 0, 0, 0, 0};
    if (t < 49) {
      const size_t off = (size_t)(base_row + (t / 7) * 56 + (t % 7)) * NQKV
                         + 768 + head * HDIM + d0;
      v = *(const bhalf8*)(qkv + off);
    }
    #pragma unroll
    for (int j = 0; j < 8; ++j) {
      const int d = d0 + j;
      const int byteoff = ((d * 64 + t) * 2) ^ ((d & 7) << 4);
      *(ushort*)(Vt + byteoff) = (ushort)v[j];
    }
  }

  // ---- Q/K fragments direct from global ----
  bhalf8 qf[4], kf[4];
  #pragma unroll
  for (int f = 0; f < 4; ++f) {
    const int r = f * 16 + l15;
    const int rr = r < 49 ? r : 48;
    const size_t off = (size_t)(base_row + (rr / 7) * 56 + (rr % 7)) * NQKV
                       + head * HDIM + l16 * 8;
    qf[f] = *(const bhalf8*)(qkv + off);
    kf[f] = *(const bhalf8*)(qkv + off + 384);
  }

  // ---- S = Q @ K^T ----
  const f32x4 fz = {};
  f32x4 s[4][4];
  #pragma unroll
  for (int fm = 0; fm < 4; ++fm)
    #pragma unroll
    for (int fn = 0; fn < 4; ++fn)
      s[fm][fn] = __builtin_amdgcn_mfma_f32_16x16x32_bf16(qf[fm], kf[fn], fz, 0, 0, 0);

  // ---- softmax (16-lane groups per row), bias added AFTER softmax ----
  const float scale = 0.17677669529663687f;
  const int colv[4] = {l15, 16 + l15, 32 + l15, 48 + l15};
  const float* brow_base = biasx + (size_t)head * 2401;

  #pragma unroll
  for (int fm = 0; fm < 4; ++fm) {
    #pragma unroll
    for (int i = 0; i < 4; ++i) {
      const int r = fm * 16 + l16 * 4 + i;
      float val[4];
      float mx = -1e30f;
      #pragma unroll
      for (int fn = 0; fn < 4; ++fn) {
        val[fn] = s[fm][fn][i] * scale;
        if (colv[fn] < 49) mx = fmaxf(mx, val[fn]);
      }
      #pragma unroll
      for (int off = 1; off < 16; off <<= 1) mx = fmaxf(mx, __shfl_xor(mx, off));
      float e[4]; float sum = 0.f;
      #pragma unroll
      for (int fn = 0; fn < 4; ++fn) {
        e[fn] = (colv[fn] < 49) ? __expf(val[fn] - mx) : 0.f;
        sum += e[fn];
      }
      #pragma unroll
      for (int off = 1; off < 16; off <<= 1) sum += __shfl_xor(sum, off);
      const float inv = 1.f / sum;
      const float* brow = brow_base + r * 49;
      #pragma unroll
      for (int fn = 0; fn < 4; ++fn) {
        const int c = colv[fn];
        float a = 0.f;
        if (r < 49 && c < 49) a = e[fn] * inv + brow[c];
        const int byteoff = ((r * 64 + c) * 2) ^ ((r & 7) << 4);
        *(ushort*)(Ps + byteoff) = f2bf(a);
      }
    }
  }

  // ---- O = P @ V ----
  f32x4 o[4][2] = {};
  #pragma unroll
  for (int kk = 0; kk < 64; kk += 32) {
    bhalf8 pf[4], vf[2];
    #pragma unroll
    for (int f = 0; f < 4; ++f) {
      const int r = f * 16 + l15;
      pf[f] = *(const bhalf8*)(Ps + (((r * 64 + kk + l16 * 8) * 2) ^ ((r & 7) << 4)));
    }
    #pragma unroll
    for (int f = 0; f < 2; ++f) {
      const int d = f * 16 + l15;
      vf[f] = *(const bhalf8*)(Vt + (((d * 64 + kk + l16 * 8) * 2) ^ ((d & 7) << 4)));
    }
    #pragma unroll
    for (int fm = 0; fm < 4; ++fm)
      #pragma unroll
      for (int fn = 0; fn < 2; ++fn)
        o[fm][fn] = __builtin_amdgcn_mfma_f32_16x16x32_bf16(pf[fm], vf[fn], o[fm][fn], 0, 0, 0);
  }

  // ---- store O ----
  #pragma unroll
  for (int fm = 0; fm < 4; ++fm) {
    #pragma unroll
    for (int i = 0; i < 4; ++i) {
      const int r = fm * 16 + l16 * 4 + i;
      if (r < 49) {
        const int grow = base_row + (r / 7) * 56 + (r % 7);
        #pragma unroll
        for (int fn = 0; fn < 2; ++fn) {
          const int d = fn * 16 + l15;
          attn_out[(size_t)grow * HID + head * HDIM + d] = f2bf(o[fm][fn][i]);
        }
      }
    }
  }
}

extern "C" void kernel_launch(void* const* d_in, const int* in_sizes, int n_in,
                              void* d_out, int out_size, void* d_ws, size_t ws_size,
                              hipStream_t stream) {
  const float* x          = (const float*)d_in[0];
  const float* w_qkv      = (const float*)d_in[1];
  const float* w_out      = (const float*)d_in[2];
  const float* b_out      = (const float*)d_in[3];
  const float* bias_table = (const float*)d_in[4];
  float* out = (float*)d_out;

  // ws layout (ushorts): xb | qkv | wqkvT | woutT | biasx(f32)
  ushort* xb     = (ushort*)d_ws;                       // [TOK][384]  bf16
  ushort* qkv    = xb + (size_t)TOK * HID;              // [TOK][1152] bf16
  ushort* wqkvT  = qkv + (size_t)TOK * NQKV;            // [1152][384] bf16
  ushort* woutT  = wqkvT + (size_t)NQKV * HID;          // [384][384]  bf16
  float*  biasx  = (float*)(woutT + (size_t)HID * HID); // [12][49][49] f32
  ushort* attn_o = xb;                                  // alias (xb dead after GEMM1)

  // 0) conversions
  {
    const int n8 = TOK * HID / 8;
    cvt_bf16<<<dim3((n8 + 255) / 256), dim3(256), 0, stream>>>(x, xb, n8);
    transpose_cvt<<<dim3(HID * NQKV / 256), dim3(256), 0, stream>>>(w_qkv, wqkvT, HID, NQKV);
    transpose_cvt<<<dim3(HID * HID / 256), dim3(256), 0, stream>>>(w_out, woutT, HID, HID);
    expand_bias<<<dim3((NHEADS * 2401 + 255) / 256), dim3(256), 0, stream>>>(bias_table, biasx);
  }

  // 1) qkv = xb @ wqkvT^T   (M=100352, N=1152, K=384)
  gemm_bt<false><<<dim3((NQKV / 128) * (TOK / 128)), dim3(256), 0, stream>>>(
      xb, wqkvT, nullptr, qkv, NQKV, HID, NQKV / 128);

  // 2) window attention: 4 waves/block, one (window, head) per wave
  win_attn2<<<dim3(2048 * NHEADS / 4), dim3(256), 0, stream>>>(qkv, biasx, attn_o);

  // 3) out = attn_o @ woutT^T + b_out  (M=100352, N=384, K=384), fp32 out
  gemm_bt<true><<<dim3((HID / 128) * (TOK / 128)), dim3(256), 0, stream>>>(
      attn_o, woutT, b_out, out, HID, HID, HID / 128);
}